// Round 11
// baseline (1002.823 us; speedup 1.0000x reference)
//
#include <hip/hip_runtime.h>
#include <hip/hip_bf16.h>
#include <math.h>

// Problem constants (fixed by setup_inputs)
#define M_TOTAL 6272   // B*P
#define N_CS    16384  // coreset rows
#define D_DIM   384
#define BATCH   8
#define P_PATCH 784
#define KNN     9

// MFMA GEMM tiling: 256x256 tile, 4 waves (2x2 of 128x128), BK=32, dbuf
#define MPAD    6400             // M padded to 256 multiple (zeros)
#define MTILES  (MPAD / 256)     // 25
#define NTILES2 (N_CS / 256)     // 64 -> pvals[m][64]
#define NBLK    (M_TOTAL / 4)    // 1568 reduce blocks; 784=4*196 -> one batch/block
#define PBB     196              // partial entries per batch

typedef _Float16 half8 __attribute__((ext_vector_type(8)));
typedef float    floatx4 __attribute__((ext_vector_type(4)));

// async global->LDS, 16B per lane; LDS dest must be uniform-base + lane*16
__device__ __forceinline__ void async_copy16(const void* g, void* l) {
    __builtin_amdgcn_global_load_lds(
        (const __attribute__((address_space(1))) void*)g,
        (__attribute__((address_space(3))) void*)l, 16, 0, 0);
}

__device__ __forceinline__ unsigned long long shfl_xor_u64(unsigned long long v, int mk) {
    int lo = __shfl_xor((int)(unsigned)v, mk, 64);
    int hi = __shfl_xor((int)(unsigned)(v >> 32), mk, 64);
    return ((unsigned long long)(unsigned)hi << 32) | (unsigned)lo;
}

// ---------------- convert fp32->f16, fused cs+emb (wave per row) ----------
// rows [0,N_CS) -> csh (+cnorm); [N_CS, N_CS+M_TOTAL) -> embh;
// [N_CS+M_TOTAL, N_CS+MPAD) -> zero-fill pad rows of embh.
__global__ void convert_all_kernel(const float* __restrict__ emb,
                                   const float* __restrict__ cs,
                                   _Float16* __restrict__ embh,
                                   _Float16* __restrict__ csh,
                                   float* __restrict__ cnorm) {
    int w = threadIdx.x >> 6, lane = threadIdx.x & 63;
    int row = blockIdx.x * 4 + w;
    if (row >= N_CS + MPAD) return;
    if (row >= N_CS + M_TOTAL) {   // zero pad rows
        unsigned* dst = (unsigned*)(embh + (size_t)(row - N_CS) * D_DIM) + lane * 3;
        dst[0] = 0u; dst[1] = 0u; dst[2] = 0u;
        return;
    }
    bool is_cs = row < N_CS;
    const float* r = (is_cs ? cs + (size_t)row * D_DIM
                            : emb + (size_t)(row - N_CS) * D_DIM) + lane * 6;
    float2 a = *(const float2*)r;
    float2 b = *(const float2*)(r + 2);
    float2 c = *(const float2*)(r + 4);
    union { _Float16 h[2]; unsigned u; } p0, p1, p2;
    p0.h[0] = (_Float16)a.x; p0.h[1] = (_Float16)a.y;
    p1.h[0] = (_Float16)b.x; p1.h[1] = (_Float16)b.y;
    p2.h[0] = (_Float16)c.x; p2.h[1] = (_Float16)c.y;
    unsigned* dst = (unsigned*)(is_cs ? csh + (size_t)row * D_DIM
                                      : embh + (size_t)(row - N_CS) * D_DIM) + lane * 3;
    dst[0] = p0.u; dst[1] = p1.u; dst[2] = p2.u;
    if (is_cs) {
        float s = a.x * a.x + a.y * a.y + b.x * b.x + b.y * b.y + c.x * c.x + c.y * c.y;
#pragma unroll
        for (int mk = 1; mk <= 32; mk <<= 1) s += __shfl_xor(s, mk, 64);
        if (lane == 0) cnorm[row] = s;
    }
}

// --------------------------------------------- MFMA GEMM + min/argmin ----
// R11: 256x256 tile (M padded to 6400), 4 waves of 128x128, acc[8][8].
// 2x MFMA per barrier vs R9's 128x256 — the barrier/drain cost that R9's
// counters showed as the residual stall amortizes over twice the work.
// dbuf LDS 64 KB (2 blocks/CU); loads issued AFTER the drain barrier so
// the compiler's vmcnt(0)-before-s_barrier waits on loads that had a full
// compute phase in flight (R9: +8% from this). XCD remap keeps each
// XCD's 1.5 MB B-set L2-resident (R7: FETCH 191->25 MB). R10 lesson: NO
// direct global->VGPR fragments — 16-line gathers per load, 245 us.
// __launch_bounds__(256,2): DO NOT raise (R6: VGPR squeeze -> acc spill).
__global__ __launch_bounds__(256, 2) void mindist_mfma_kernel(
    const _Float16* __restrict__ embh, const _Float16* __restrict__ csh,
    const float* __restrict__ cnorm,
    float* __restrict__ pvals, int* __restrict__ pidx) {
    __shared__ _Float16 As0[256 * 32];   // 16 KB
    __shared__ _Float16 As1[256 * 32];   // 16 KB
    __shared__ _Float16 Bs0[256 * 32];   // 16 KB
    __shared__ _Float16 Bs1[256 * 32];   // 16 KB

    const int b    = blockIdx.x;
    const int bx   = b >> 6;                               // 0..24
    const int by   = ((b & 7) << 3) | ((b >> 3) & 7);      // 0..63 (XCD-major)
    const int tid  = threadIdx.x;
    const int lane = tid & 63;
    const int w    = tid >> 6;
    const int wr   = w >> 1, wc = w & 1;
    const int row0  = bx * 256;
    const int cbase = by * 256;
    const int q   = lane >> 4;
    const int cl  = lane & 15;

    floatx4 acc[8][8];
#pragma unroll
    for (int mi = 0; mi < 8; ++mi)
#pragma unroll
        for (int nj = 0; nj < 8; ++nj) acc[mi][nj] = (floatx4){0.f, 0.f, 0.f, 0.f};

    float cn_l[8];
#pragma unroll
    for (int nj = 0; nj < 8; ++nj)
        cn_l[nj] = cnorm[cbase + wc * 128 + nj * 16 + cl];

    const int sub4 = lane >> 2;         // row within 16-row staging block
    const int ch   = lane & 3;          // dest 16B chunk

    // stage one BK=32 chunk (A 16 KB + B 16 KB) into (AS,BS)
#define STAGE(AS, BS, KK)                                                     \
    {                                                                         \
        _Pragma("unroll")                                                     \
        for (int i = 0; i < 8; ++i) {                                         \
            int inst = w * 8 + i;       /* 0..31: 16 A + 16 B */              \
            if (inst < 16) {                                                  \
                int r  = inst * 16 + sub4;                                    \
                int sc = (ch ^ ((r >> 1) & 3)) * 8;                           \
                async_copy16(embh + (size_t)(row0 + r) * D_DIM + (KK) + sc,   \
                             &AS[inst * 512 + lane * 8]);                     \
            } else {                                                          \
                int blk = inst - 16;                                          \
                int r   = blk * 16 + sub4;                                    \
                int sc  = (ch ^ ((r >> 1) & 3)) * 8;                          \
                async_copy16(csh + (size_t)(cbase + r) * D_DIM + (KK) + sc,   \
                             &BS[blk * 512 + lane * 8]);                      \
            }                                                                 \
        }                                                                     \
    }

#define COMPUTE(AS, BS)                                                       \
    {                                                                         \
        half8 af[8], bf[8];                                                   \
        _Pragma("unroll")                                                     \
        for (int mi = 0; mi < 8; ++mi) {                                      \
            int R = wr * 128 + mi * 16 + cl;                                  \
            af[mi] = *(const half8*)&AS[R * 32 + ((q ^ ((R >> 1) & 3)) * 8)]; \
        }                                                                     \
        _Pragma("unroll")                                                     \
        for (int nj = 0; nj < 8; ++nj) {                                      \
            int R = wc * 128 + nj * 16 + cl;                                  \
            bf[nj] = *(const half8*)&BS[R * 32 + ((q ^ ((R >> 1) & 3)) * 8)]; \
        }                                                                     \
        _Pragma("unroll")                                                     \
        for (int mi = 0; mi < 8; ++mi)                                        \
            _Pragma("unroll")                                                 \
            for (int nj = 0; nj < 8; ++nj)                                    \
                acc[mi][nj] = __builtin_amdgcn_mfma_f32_16x16x32_f16(         \
                    af[mi], bf[nj], acc[mi][nj], 0, 0, 0);                    \
    }

    // 12 chunks of K=32; barrier -> prefetch other buf -> compute current.
    STAGE(As0, Bs0, 0);
#pragma unroll 1
    for (int jj = 0; jj < 5; ++jj) {
        int kk = jj * 64;
        __syncthreads();                 // drains chunk kk (buf0)
        STAGE(As1, Bs1, kk + 32);        // flies during compute
        COMPUTE(As0, Bs0);
        __syncthreads();                 // drains chunk kk+32 (buf1)
        STAGE(As0, Bs0, kk + 64);
        COMPUTE(As1, Bs1);
    }
    __syncthreads();
    STAGE(As1, Bs1, 352);
    COMPUTE(As0, Bs0);   // chunk 320
    __syncthreads();
    COMPUTE(As1, Bs1);   // chunk 352
#undef STAGE
#undef COMPUTE

    // epilogue: per-row min/argmin over the 256-wide tile (scratch in As0)
    float* smv = (float*)As0;            // [256][2] = 2 KB
    int*   smi = (int*)(As0 + 1024);     // next 2 KB
    // waves still in the last COMPUTE only touch As1/Bs1 — no conflict.
#pragma unroll
    for (int mi = 0; mi < 8; ++mi) {
#pragma unroll
        for (int r = 0; r < 4; ++r) {
            float v = 3.4e38f; int idx = 0x7fffffff;
#pragma unroll
            for (int nj = 0; nj < 8; ++nj) {   // ascending col per lane, strict <
                float d = cn_l[nj] - 2.f * acc[mi][nj][r];
                int   c = cbase + wc * 128 + nj * 16 + cl;
                if (d < v) { v = d; idx = c; }
            }
#pragma unroll
            for (int mk = 1; mk <= 8; mk <<= 1) {
                float v2 = __shfl_xor(v, mk, 64);
                int   i2 = __shfl_xor(idx, mk, 64);
                if (v2 < v || (v2 == v && i2 < idx)) { v = v2; idx = i2; }
            }
            if (cl == 0) {
                int rl = wr * 128 + mi * 16 + q * 4 + r;   // 0..255
                smv[rl * 2 + wc] = v;
                smi[rl * 2 + wc] = idx;
            }
        }
    }
    __syncthreads();
    {
        float v = smv[tid * 2];      int i = smi[tid * 2];
        float v1 = smv[tid * 2 + 1]; int i1 = smi[tid * 2 + 1];
        if (v1 < v) { v = v1; i = i1; }   // wc0 indices always < wc1 indices
        pvals[(size_t)(row0 + tid) * NTILES2 + by] = v;
        pidx[(size_t)(row0 + tid) * NTILES2 + by]  = i;
    }
}

// ---- partial-min reduce + EXACT fp32 rescore + block-level argmax -------
// partial[block] = max over the block's 4 rows of (score_bits<<32)|(~patch):
// NO atomics (R7: 1568 device atomicMax on one 64B line bounced across
// XCDs, ~65 us serialization). dnn/top9 re-scan the 12.5 KB array instead.
__global__ void reduce_rescore_kernel(const float* __restrict__ pvals,
                                      const int* __restrict__ pidx,
                                      const float* __restrict__ emb,
                                      const float* __restrict__ cs,
                                      int* __restrict__ loc,
                                      unsigned long long* __restrict__ partial) {
    __shared__ unsigned long long keys[4];
    int w = threadIdx.x >> 6, lane = threadIdx.x & 63;
    int m = blockIdx.x * 4 + w;
    float v = pvals[(size_t)m * NTILES2 + lane];
    int   i = pidx[(size_t)m * NTILES2 + lane];
#pragma unroll
    for (int mk = 1; mk <= 32; mk <<= 1) {
        float v2 = __shfl_xor(v, mk, 64);
        int   i2 = __shfl_xor(i, mk, 64);
        if (v2 < v || (v2 == v && i2 < i)) { v = v2; i = i2; }
    }
    // exact fp32 distance to the selected coreset row
    const float* a = emb + (size_t)m * D_DIM;
    const float* bp = cs + (size_t)i * D_DIM;
    float s = 0.f;
#pragma unroll
    for (int t = 0; t < D_DIM / 64; ++t) {
        float d = a[lane + t * 64] - bp[lane + t * 64];
        s += d * d;
    }
#pragma unroll
    for (int mk = 1; mk <= 32; mk <<= 1) s += __shfl_xor(s, mk, 64);
    if (lane == 0) {
        float sc = sqrtf(s);
        loc[m] = i;
        int p = m % P_PATCH;
        keys[w] = ((unsigned long long)__float_as_uint(sc) << 32) |
                  (unsigned)(0x7fffffff - p);
    }
    __syncthreads();
    if (threadIdx.x == 0) {
        unsigned long long k = keys[0];
        if (keys[1] > k) k = keys[1];
        if (keys[2] > k) k = keys[2];
        if (keys[3] > k) k = keys[3];
        partial[blockIdx.x] = k;
    }
}

// -------------------- d_nn: 8 queries x 16384 coreset (coalesced GEMV) ----
__global__ void dnn_kernel(const float* __restrict__ cs,
                           const float* __restrict__ cnorm,
                           const unsigned long long* __restrict__ partial,
                           const int* __restrict__ loc,
                           float* __restrict__ dmat) {
    __shared__ int bnnS[BATCH];
    {   // per-block argmax recompute: 32 lanes per batch over 196 entries
        int bb = threadIdx.x >> 5, l32 = threadIdx.x & 31;
        unsigned long long best = 0ull;
        for (int j = l32; j < PBB; j += 32) {
            unsigned long long k = partial[bb * PBB + j];
            if (k > best) best = k;
        }
#pragma unroll
        for (int mk = 1; mk <= 16; mk <<= 1) {
            unsigned long long o = shfl_xor_u64(best, mk);
            if (o > best) best = o;
        }
        if (l32 == 0) {
            int p = 0x7fffffff - (unsigned)(best & 0xffffffffull);
            bnnS[bb] = loc[bb * P_PATCH + p];
        }
    }
    __syncthreads();

    int lane = threadIdx.x & 63;
    int gw = (blockIdx.x * 256 + threadIdx.x) >> 6;  // 0..1023
    float qv[BATCH][6];
#pragma unroll
    for (int b = 0; b < BATCH; ++b) {
        const float* qr = cs + (size_t)bnnS[b] * D_DIM + lane * 6;
#pragma unroll
        for (int j = 0; j < 6; ++j) qv[b][j] = qr[j];
    }
    for (int n = gw; n < N_CS; n += 1024) {
        const float* r = cs + (size_t)n * D_DIM + lane * 6;
        float x[6];
#pragma unroll
        for (int j = 0; j < 6; ++j) x[j] = r[j];
        float s[BATCH];
#pragma unroll
        for (int b = 0; b < BATCH; ++b) {
            float t = 0.f;
#pragma unroll
            for (int j = 0; j < 6; ++j) t += x[j] * qv[b][j];
            s[b] = t;
        }
#pragma unroll
        for (int b = 0; b < BATCH; ++b)
#pragma unroll
            for (int mk = 1; mk <= 32; mk <<= 1) s[b] += __shfl_xor(s[b], mk, 64);
        if (lane < BATCH) {
            float sv = s[0];
#pragma unroll
            for (int b = 1; b < BATCH; ++b) sv = (lane == b) ? s[b] : sv;
            dmat[(size_t)lane * N_CS + n] = cnorm[n] - 2.f * sv;  // -qnorm shift: order-safe
        }
    }
}

// ----------------------- top-9 merge + exact dsup + softmax weighting ----
__device__ inline void merge9(float* av, int* ai, const float* bv, const int* bi) {
    float mv[KNN]; int mi[KNN];
    int x = 0, y = 0;
#pragma unroll
    for (int k = 0; k < KNN; ++k) {
        bool ta = (av[x] < bv[y]) || (av[x] == bv[y] && ai[x] < bi[y]);
        if (ta) { mv[k] = av[x]; mi[k] = ai[x]; ++x; }
        else    { mv[k] = bv[y]; mi[k] = bi[y]; ++y; }
    }
#pragma unroll
    for (int k = 0; k < KNN; ++k) { av[k] = mv[k]; ai[k] = mi[k]; }
}

__global__ void top9_final_kernel(const float* __restrict__ dmat,
                                  const float* __restrict__ emb,
                                  const float* __restrict__ cs,
                                  const unsigned long long* __restrict__ partial,
                                  float* __restrict__ out) {
    int b = blockIdx.x;
    int tid = threadIdx.x;  // 512
    __shared__ float lv[512][KNN];
    __shared__ int   li[512][KNN];
    __shared__ float mf[D_DIM];
    __shared__ float dsup[KNN];
    __shared__ float bscoreS;
    __shared__ int   bpatchS;

    if (tid < 64) {  // argmax recompute for this batch
        unsigned long long best = 0ull;
        for (int j = tid; j < PBB; j += 64) {
            unsigned long long k = partial[b * PBB + j];
            if (k > best) best = k;
        }
#pragma unroll
        for (int mk = 1; mk <= 32; mk <<= 1) {
            unsigned long long o = shfl_xor_u64(best, mk);
            if (o > best) best = o;
        }
        if (tid == 0) {
            bpatchS = 0x7fffffff - (unsigned)(best & 0xffffffffull);
            bscoreS = __uint_as_float((unsigned)(best >> 32));
        }
    }
    __syncthreads();
    int mp = bpatchS;
    const float* frow = emb + (size_t)(b * P_PATCH + mp) * D_DIM;
    for (int i = tid; i < D_DIM; i += 512) mf[i] = frow[i];

    float tv[KNN]; int ti[KNN];
#pragma unroll
    for (int k = 0; k < KNN; ++k) { tv[k] = 3.4e38f; ti[k] = 0x7fffffff; }
    for (int n = tid; n < N_CS; n += 512) {   // ascending n per thread
        float d = dmat[(size_t)b * N_CS + n];
        if (d < tv[KNN - 1] || (d == tv[KNN - 1] && n < ti[KNN - 1])) {
            tv[KNN - 1] = d; ti[KNN - 1] = n;
#pragma unroll
            for (int k = KNN - 1; k > 0; --k) {
                if (tv[k] < tv[k - 1] || (tv[k] == tv[k - 1] && ti[k] < ti[k - 1])) {
                    float fv = tv[k]; tv[k] = tv[k - 1]; tv[k - 1] = fv;
                    int   iv = ti[k]; ti[k] = ti[k - 1]; ti[k - 1] = iv;
                }
            }
        }
    }
#pragma unroll
    for (int k = 0; k < KNN; ++k) { lv[tid][k] = tv[k]; li[tid][k] = ti[k]; }
    __syncthreads();
    for (int off = 256; off > 0; off >>= 1) {
        if (tid < off) {
            float av[KNN]; int ai[KNN]; float bv2[KNN]; int bi2[KNN];
#pragma unroll
            for (int k = 0; k < KNN; ++k) {
                av[k]  = lv[tid][k];        ai[k]  = li[tid][k];
                bv2[k] = lv[tid + off][k];  bi2[k] = li[tid + off][k];
            }
            merge9(av, ai, bv2, bi2);
#pragma unroll
            for (int k = 0; k < KNN; ++k) { lv[tid][k] = av[k]; li[tid][k] = ai[k]; }
        }
        __syncthreads();
    }
    // exact fp32 distances to the 9 support rows: 32 lanes per neighbor
    {
        int k      = tid >> 5;   // 0..15
        int lane32 = tid & 31;
        if (k < KNN) {
            int idx = li[0][k];
            const float* r = cs + (size_t)idx * D_DIM;
            float s = 0.f;
            for (int i = lane32; i < D_DIM; i += 32) {
                float df = mf[i] - r[i];
                s += df * df;
            }
#pragma unroll
            for (int mk = 1; mk <= 16; mk <<= 1) s += __shfl_xor(s, mk, 64);
            if (lane32 == 0) dsup[k] = sqrtf(fmaxf(s, 0.f));
        }
    }
    __syncthreads();
    if (tid == 0) {
        float mx = dsup[0];
        for (int k = 1; k < KNN; ++k) mx = fmaxf(mx, dsup[k]);
        float sum = 0.f, e0 = 0.f;
        for (int k = 0; k < KNN; ++k) {
            float e = expf(dsup[k] - mx);
            sum += e;
            if (k == 0) e0 = e;
        }
        out[b] = (1.f - e0 / sum) * bscoreS;
    }
}

// ------------------------------------------------------------- launcher ----
extern "C" void kernel_launch(void* const* d_in, const int* in_sizes, int n_in,
                              void* d_out, int out_size, void* d_ws, size_t ws_size,
                              hipStream_t stream) {
    (void)in_sizes; (void)n_in; (void)out_size; (void)ws_size;
    const float* emb = (const float*)d_in[0];
    const float* cs  = (const float*)d_in[1];
    float* out = (float*)d_out;

    // workspace layout
    char* p = (char*)d_ws;
    float* cnorm  = (float*)p;  p += (size_t)N_CS * 4;                     // 64 KB
    float* pvals  = (float*)p;  p += (size_t)MPAD * NTILES2 * 4;           // 1.64 MB
    int*   pidx   = (int*)p;    p += (size_t)MPAD * NTILES2 * 4;           // 1.64 MB
    int*   loc    = (int*)p;    p += (size_t)M_TOTAL * 4;
    p = (char*)(((size_t)p + 7) & ~(size_t)7);
    unsigned long long* partial = (unsigned long long*)p; p += NBLK * 8;   // 12.5 KB
    float* dmat   = (float*)p;  p += (size_t)BATCH * N_CS * 4;             // 512 KB
    p = (char*)(((size_t)p + 15) & ~(size_t)15);
    _Float16* embh = (_Float16*)p; p += (size_t)MPAD * D_DIM * 2;          // 4.9 MB
    _Float16* csh  = (_Float16*)p; p += (size_t)N_CS * D_DIM * 2;          // 12.6 MB

    {
        int rows = N_CS + MPAD;
        convert_all_kernel<<<(rows + 3) / 4, 256, 0, stream>>>(emb, cs, embh, csh, cnorm);
    }
    mindist_mfma_kernel<<<MTILES * 64, 256, 0, stream>>>(embh, csh, cnorm,
                                                         pvals, pidx);
    reduce_rescore_kernel<<<NBLK, 256, 0, stream>>>(pvals, pidx, emb, cs, loc, partial);
    dnn_kernel<<<256, 256, 0, stream>>>(cs, cnorm, partial, loc, dmat);
    top9_final_kernel<<<BATCH, 512, 0, stream>>>(dmat, emb, cs, partial, out);
}

// Round 12
// 448.992 us; speedup vs baseline: 2.2335x; 2.2335x over previous
//
#include <hip/hip_runtime.h>
#include <hip/hip_bf16.h>
#include <math.h>

// Problem constants (fixed by setup_inputs)
#define M_TOTAL 6272   // B*P
#define N_CS    16384  // coreset rows
#define D_DIM   384
#define BATCH   8
#define P_PATCH 784
#define KNN     9

// MFMA GEMM tiling: 128x256 tile, 4 waves (2x2 of 64x128), BK=32, dbuf (R9)
#define MTILES  (M_TOTAL / 128)  // 49
#define NTILES2 (N_CS / 256)     // 64 -> pvals[m][64]
#define NBLK    (M_TOTAL / 4)    // 1568 reduce blocks; 784=4*196 -> one batch/block
#define PBB     196              // partial entries per batch
#define KSL     16               // knn slices per batch
#define KROWS   (N_CS / KSL)     // 1024

typedef _Float16 half8 __attribute__((ext_vector_type(8)));
typedef float    floatx4 __attribute__((ext_vector_type(4)));

// async global->LDS, 16B per lane; LDS dest must be uniform-base + lane*16
__device__ __forceinline__ void async_copy16(const void* g, void* l) {
    __builtin_amdgcn_global_load_lds(
        (const __attribute__((address_space(1))) void*)g,
        (__attribute__((address_space(3))) void*)l, 16, 0, 0);
}

__device__ __forceinline__ unsigned long long shfl_xor_u64(unsigned long long v, int mk) {
    int lo = __shfl_xor((int)(unsigned)v, mk, 64);
    int hi = __shfl_xor((int)(unsigned)(v >> 32), mk, 64);
    return ((unsigned long long)(unsigned)hi << 32) | (unsigned)lo;
}

// ---------------- convert fp32->f16, fused cs+emb (wave per row) ----------
__global__ void convert_all_kernel(const float* __restrict__ emb,
                                   const float* __restrict__ cs,
                                   _Float16* __restrict__ embh,
                                   _Float16* __restrict__ csh,
                                   float* __restrict__ cnorm) {
    int w = threadIdx.x >> 6, lane = threadIdx.x & 63;
    int row = blockIdx.x * 4 + w;
    if (row >= N_CS + M_TOTAL) return;
    bool is_cs = row < N_CS;
    const float* r = (is_cs ? cs + (size_t)row * D_DIM
                            : emb + (size_t)(row - N_CS) * D_DIM) + lane * 6;
    float2 a = *(const float2*)r;
    float2 b = *(const float2*)(r + 2);
    float2 c = *(const float2*)(r + 4);
    union { _Float16 h[2]; unsigned u; } p0, p1, p2;
    p0.h[0] = (_Float16)a.x; p0.h[1] = (_Float16)a.y;
    p1.h[0] = (_Float16)b.x; p1.h[1] = (_Float16)b.y;
    p2.h[0] = (_Float16)c.x; p2.h[1] = (_Float16)c.y;
    unsigned* dst = (unsigned*)(is_cs ? csh + (size_t)row * D_DIM
                                      : embh + (size_t)(row - N_CS) * D_DIM) + lane * 3;
    dst[0] = p0.u; dst[1] = p1.u; dst[2] = p2.u;
    if (is_cs) {
        float s = a.x * a.x + a.y * a.y + b.x * b.x + b.y * b.y + c.x * c.x + c.y * c.y;
#pragma unroll
        for (int mk = 1; mk <= 32; mk <<= 1) s += __shfl_xor(s, mk, 64);
        if (lane == 0) cnorm[row] = s;
    }
}

// --------------------------------------------- MFMA GEMM + min/argmin ----
// R9 config verbatim (best measured: 137 us). 128x256 tile, BK=32, dbuf
// with loads issued AFTER the drain barrier; XCD remap; XOR swizzle.
// R6 lesson: never raise launch_bounds (VGPR squeeze -> acc spill).
// R10 lesson: no direct global->VGPR fragments (16-line gathers, 245 us).
// R11 lesson: acc must stay <=128 VGPR/wave at 2 waves/SIMD (acc[8][8]
// spilled 1.8 GB, 804 us).
__global__ __launch_bounds__(256, 2) void mindist_mfma_kernel(
    const _Float16* __restrict__ embh, const _Float16* __restrict__ csh,
    const float* __restrict__ cnorm,
    float* __restrict__ pvals, int* __restrict__ pidx) {
    __shared__ _Float16 As0[128 * 32];   // 8 KB
    __shared__ _Float16 As1[128 * 32];   // 8 KB
    __shared__ _Float16 Bs0[256 * 32];   // 16 KB
    __shared__ _Float16 Bs1[256 * 32];   // 16 KB

    const int b    = blockIdx.x;
    const int bx   = b >> 6;                               // 0..48
    const int by   = ((b & 7) << 3) | ((b >> 3) & 7);      // 0..63 (XCD-major)
    const int tid  = threadIdx.x;
    const int lane = tid & 63;
    const int w    = tid >> 6;
    const int wr   = w >> 1, wc = w & 1;
    const int row0  = bx * 128;
    const int cbase = by * 256;
    const int q   = lane >> 4;
    const int cl  = lane & 15;

    floatx4 acc[4][8];
#pragma unroll
    for (int mi = 0; mi < 4; ++mi)
#pragma unroll
        for (int nj = 0; nj < 8; ++nj) acc[mi][nj] = (floatx4){0.f, 0.f, 0.f, 0.f};

    float cn_l[8];
#pragma unroll
    for (int nj = 0; nj < 8; ++nj)
        cn_l[nj] = cnorm[cbase + wc * 128 + nj * 16 + cl];

    const int sub4 = lane >> 2;         // row within 16-row staging block
    const int ch   = lane & 3;          // dest 16B chunk

#define STAGE(AS, BS, KK)                                                     \
    {                                                                         \
        _Pragma("unroll")                                                     \
        for (int i = 0; i < 6; ++i) {                                         \
            int inst = w * 6 + i;                                             \
            if (inst < 8) {                                                   \
                int r  = inst * 16 + sub4;                                    \
                int sc = (ch ^ ((r >> 1) & 3)) * 8;                           \
                async_copy16(embh + (size_t)(row0 + r) * D_DIM + (KK) + sc,   \
                             &AS[inst * 512 + lane * 8]);                     \
            } else {                                                          \
                int blk = inst - 8;                                           \
                int r   = blk * 16 + sub4;                                    \
                int sc  = (ch ^ ((r >> 1) & 3)) * 8;                          \
                async_copy16(csh + (size_t)(cbase + r) * D_DIM + (KK) + sc,   \
                             &BS[blk * 512 + lane * 8]);                      \
            }                                                                 \
        }                                                                     \
    }

#define COMPUTE(AS, BS)                                                       \
    {                                                                         \
        half8 af[4], bf[8];                                                   \
        _Pragma("unroll")                                                     \
        for (int mi = 0; mi < 4; ++mi) {                                      \
            int R = wr * 64 + mi * 16 + cl;                                   \
            af[mi] = *(const half8*)&AS[R * 32 + ((q ^ ((R >> 1) & 3)) * 8)]; \
        }                                                                     \
        _Pragma("unroll")                                                     \
        for (int nj = 0; nj < 8; ++nj) {                                      \
            int R = wc * 128 + nj * 16 + cl;                                  \
            bf[nj] = *(const half8*)&BS[R * 32 + ((q ^ ((R >> 1) & 3)) * 8)]; \
        }                                                                     \
        _Pragma("unroll")                                                     \
        for (int mi = 0; mi < 4; ++mi)                                        \
            _Pragma("unroll")                                                 \
            for (int nj = 0; nj < 8; ++nj)                                    \
                acc[mi][nj] = __builtin_amdgcn_mfma_f32_16x16x32_f16(         \
                    af[mi], bf[nj], acc[mi][nj], 0, 0, 0);                    \
    }

    // 12 chunks of K=32; barrier -> prefetch other buf -> compute current.
    STAGE(As0, Bs0, 0);
    int kk = 0;
#pragma unroll 1
    for (int jj = 0; jj < 5; ++jj) {
        __syncthreads();                 // drain chunk kk (buf0)
        STAGE(As1, Bs1, kk + 32);        // prefetch: flies during compute
        COMPUTE(As0, Bs0);
        __syncthreads();                 // drain chunk kk+32 (buf1)
        STAGE(As0, Bs0, kk + 64);
        COMPUTE(As1, Bs1);
        kk += 64;
    }
    __syncthreads();
    STAGE(As1, Bs1, kk + 32);
    COMPUTE(As0, Bs0);
    __syncthreads();
    COMPUTE(As1, Bs1);
#undef STAGE
#undef COMPUTE

    // epilogue: per-row min/argmin over the 256-wide tile
    __syncthreads();
    float* smv = (float*)As0;           // [128][2] (1 KB)
    int*   smi = (int*)(As0 + 512);     // 1 KB past smv

#pragma unroll
    for (int mi = 0; mi < 4; ++mi) {
#pragma unroll
        for (int r = 0; r < 4; ++r) {
            float v = 3.4e38f; int idx = 0x7fffffff;
#pragma unroll
            for (int nj = 0; nj < 8; ++nj) {   // ascending col per lane, strict <
                float d = cn_l[nj] - 2.f * acc[mi][nj][r];
                int   c = cbase + wc * 128 + nj * 16 + cl;
                if (d < v) { v = d; idx = c; }
            }
#pragma unroll
            for (int mk = 1; mk <= 8; mk <<= 1) {
                float v2 = __shfl_xor(v, mk, 64);
                int   i2 = __shfl_xor(idx, mk, 64);
                if (v2 < v || (v2 == v && i2 < idx)) { v = v2; idx = i2; }
            }
            if (cl == 0) {
                int rl = wr * 64 + mi * 16 + q * 4 + r;
                smv[rl * 2 + wc] = v;
                smi[rl * 2 + wc] = idx;
            }
        }
    }
    __syncthreads();
    if (tid < 128) {
        float v = smv[tid * 2];      int i = smi[tid * 2];
        float v1 = smv[tid * 2 + 1]; int i1 = smi[tid * 2 + 1];
        if (v1 < v) { v = v1; i = i1; }   // wc0 indices always < wc1 indices
        pvals[(size_t)(row0 + tid) * NTILES2 + by] = v;
        pidx[(size_t)(row0 + tid) * NTILES2 + by]  = i;
    }
}

// ---- partial-min reduce + EXACT fp32 rescore + block-level argmax -------
// NO atomics (R7: device atomicMax on one line bounced across XCDs, ~65 us).
__global__ void reduce_rescore_kernel(const float* __restrict__ pvals,
                                      const int* __restrict__ pidx,
                                      const float* __restrict__ emb,
                                      const float* __restrict__ cs,
                                      int* __restrict__ loc,
                                      unsigned long long* __restrict__ partial) {
    __shared__ unsigned long long keys[4];
    int w = threadIdx.x >> 6, lane = threadIdx.x & 63;
    int m = blockIdx.x * 4 + w;
    float v = pvals[(size_t)m * NTILES2 + lane];
    int   i = pidx[(size_t)m * NTILES2 + lane];
#pragma unroll
    for (int mk = 1; mk <= 32; mk <<= 1) {
        float v2 = __shfl_xor(v, mk, 64);
        int   i2 = __shfl_xor(i, mk, 64);
        if (v2 < v || (v2 == v && i2 < i)) { v = v2; i = i2; }
    }
    const float* a = emb + (size_t)m * D_DIM;
    const float* bp = cs + (size_t)i * D_DIM;
    float s = 0.f;
#pragma unroll
    for (int t = 0; t < D_DIM / 64; ++t) {
        float d = a[lane + t * 64] - bp[lane + t * 64];
        s += d * d;
    }
#pragma unroll
    for (int mk = 1; mk <= 32; mk <<= 1) s += __shfl_xor(s, mk, 64);
    if (lane == 0) {
        float sc = sqrtf(s);
        loc[m] = i;
        int p = m % P_PATCH;
        keys[w] = ((unsigned long long)__float_as_uint(sc) << 32) |
                  (unsigned)(0x7fffffff - p);
    }
    __syncthreads();
    if (threadIdx.x == 0) {
        unsigned long long k = keys[0];
        if (keys[1] > k) k = keys[1];
        if (keys[2] > k) k = keys[2];
        if (keys[3] > k) k = keys[3];
        partial[blockIdx.x] = k;
    }
}

// ------------- knn partial: top-9 per (batch, slice), no dmat ------------
// R12: replaces dnn+top9 scan. 128 blocks = 8 batches x 16 slices of 1024
// rows. Wave-per-row coalesced reads; ONE query per block (6 shfl/row vs
// dnn's 48); local top-9 in registers; writes 9 candidates per block.
__device__ inline void merge9(float* av, int* ai, const float* bv, const int* bi) {
    float mv[KNN]; int mi[KNN];
    int x = 0, y = 0;
#pragma unroll
    for (int k = 0; k < KNN; ++k) {
        bool ta = (av[x] < bv[y]) || (av[x] == bv[y] && ai[x] < bi[y]);
        if (ta) { mv[k] = av[x]; mi[k] = ai[x]; ++x; }
        else    { mv[k] = bv[y]; mi[k] = bi[y]; ++y; }
    }
#pragma unroll
    for (int k = 0; k < KNN; ++k) { av[k] = mv[k]; ai[k] = mi[k]; }
}

__global__ void knn_partial_kernel(const float* __restrict__ cs,
                                   const float* __restrict__ cnorm,
                                   const unsigned long long* __restrict__ partial,
                                   const int* __restrict__ loc,
                                   float* __restrict__ kv, int* __restrict__ ki) {
    const int blk = blockIdx.x;          // 0..127
    const int bb  = blk >> 4;            // batch
    const int sl  = blk & 15;            // slice
    const int w = threadIdx.x >> 6, lane = threadIdx.x & 63;
    __shared__ int bnnS;
    __shared__ float lvS[4][KNN];
    __shared__ int   liS[4][KNN];

    if (threadIdx.x < 64) {   // recompute this batch's argmax -> nn index
        unsigned long long best = 0ull;
        for (int j = lane; j < PBB; j += 64) {
            unsigned long long k = partial[bb * PBB + j];
            if (k > best) best = k;
        }
#pragma unroll
        for (int mk = 1; mk <= 32; mk <<= 1) {
            unsigned long long o = shfl_xor_u64(best, mk);
            if (o > best) best = o;
        }
        if (lane == 0) {
            int p = 0x7fffffff - (unsigned)(best & 0xffffffffull);
            bnnS = loc[bb * P_PATCH + p];
        }
    }
    __syncthreads();

    float qv[6];
    {
        const float* qr = cs + (size_t)bnnS * D_DIM + lane * 6;
#pragma unroll
        for (int j = 0; j < 6; ++j) qv[j] = qr[j];
    }

    float tv[KNN]; int ti[KNN];
#pragma unroll
    for (int k = 0; k < KNN; ++k) { tv[k] = 3.4e38f; ti[k] = 0x7fffffff; }
    const int base = sl * KROWS;
    for (int j = 0; j < KROWS / 4; ++j) {
        int n = base + j * 4 + w;                 // ascending per wave
        const float* r = cs + (size_t)n * D_DIM + lane * 6;
        float s = r[0] * qv[0] + r[1] * qv[1] + r[2] * qv[2]
                + r[3] * qv[3] + r[4] * qv[4] + r[5] * qv[5];
#pragma unroll
        for (int mk = 1; mk <= 32; mk <<= 1) s += __shfl_xor(s, mk, 64);
        float d = cnorm[n] - 2.f * s;             // -qnorm shift: order-safe
        if (d < tv[KNN - 1] || (d == tv[KNN - 1] && n < ti[KNN - 1])) {
            tv[KNN - 1] = d; ti[KNN - 1] = n;
#pragma unroll
            for (int k = KNN - 1; k > 0; --k) {
                if (tv[k] < tv[k - 1] || (tv[k] == tv[k - 1] && ti[k] < ti[k - 1])) {
                    float fv = tv[k]; tv[k] = tv[k - 1]; tv[k - 1] = fv;
                    int   iv = ti[k]; ti[k] = ti[k - 1]; ti[k - 1] = iv;
                }
            }
        }
    }
    if (lane == 0) {
#pragma unroll
        for (int k = 0; k < KNN; ++k) { lvS[w][k] = tv[k]; liS[w][k] = ti[k]; }
    }
    __syncthreads();
    if (threadIdx.x == 0) {
        float av[KNN]; int ai[KNN];
#pragma unroll
        for (int k = 0; k < KNN; ++k) { av[k] = lvS[0][k]; ai[k] = liS[0][k]; }
        for (int ww = 1; ww < 4; ++ww) merge9(av, ai, lvS[ww], liS[ww]);
#pragma unroll
        for (int k = 0; k < KNN; ++k) {
            kv[blk * KNN + k] = av[k];
            ki[blk * KNN + k] = ai[k];
        }
    }
}

// ---------- knn final: merge 16x9 candidates + exact dsup + softmax ------
__global__ void knn_final_kernel(const float* __restrict__ kv,
                                 const int* __restrict__ ki,
                                 const float* __restrict__ emb,
                                 const float* __restrict__ cs,
                                 const unsigned long long* __restrict__ partial,
                                 float* __restrict__ out) {
    const int b = blockIdx.x;
    const int tid = threadIdx.x;   // 512
    const int NCAND = KSL * KNN;   // 144
    __shared__ float cv[NCAND];
    __shared__ int   ci[NCAND];
    __shared__ float mf[D_DIM];
    __shared__ int   sel[KNN];
    __shared__ float dsup[KNN];
    __shared__ float bscoreS;
    __shared__ int   bpatchS;

    if (tid < 64) {   // argmax recompute
        unsigned long long best = 0ull;
        for (int j = tid; j < PBB; j += 64) {
            unsigned long long k = partial[b * PBB + j];
            if (k > best) best = k;
        }
#pragma unroll
        for (int mk = 1; mk <= 32; mk <<= 1) {
            unsigned long long o = shfl_xor_u64(best, mk);
            if (o > best) best = o;
        }
        if (tid == 0) {
            bpatchS = 0x7fffffff - (unsigned)(best & 0xffffffffull);
            bscoreS = __uint_as_float((unsigned)(best >> 32));
        }
    }
    if (tid < NCAND) {
        cv[tid] = kv[b * NCAND + tid];
        ci[tid] = ki[b * NCAND + tid];
    }
    __syncthreads();
    const float* frow = emb + (size_t)(b * P_PATCH + bpatchS) * D_DIM;
    for (int i = tid; i < D_DIM; i += 512) mf[i] = frow[i];

    if (tid == 0) {   // serial select-9 from 144 (disjoint candidate sets)
        for (int k = 0; k < KNN; ++k) {
            float bv = 3.4e38f; int bi = 0x7fffffff; int bj = -1;
            for (int j = 0; j < NCAND; ++j) {
                if (cv[j] < bv || (cv[j] == bv && ci[j] < bi)) {
                    bv = cv[j]; bi = ci[j]; bj = j;
                }
            }
            sel[k] = bi;
            cv[bj] = 3.4e38f; ci[bj] = 0x7fffffff;
        }
    }
    __syncthreads();
    {
        int k = tid >> 5, lane32 = tid & 31;
        if (k < KNN) {
            const float* r = cs + (size_t)sel[k] * D_DIM;
            float s = 0.f;
            for (int i = lane32; i < D_DIM; i += 32) {
                float df = mf[i] - r[i];
                s += df * df;
            }
#pragma unroll
            for (int mk = 1; mk <= 16; mk <<= 1) s += __shfl_xor(s, mk, 64);
            if (lane32 == 0) dsup[k] = sqrtf(fmaxf(s, 0.f));
        }
    }
    __syncthreads();
    if (tid == 0) {
        float mx = dsup[0];
        for (int k = 1; k < KNN; ++k) mx = fmaxf(mx, dsup[k]);
        float sum = 0.f, e0 = 0.f;
        for (int k = 0; k < KNN; ++k) {
            float e = expf(dsup[k] - mx);
            sum += e;
            if (k == 0) e0 = e;
        }
        out[b] = (1.f - e0 / sum) * bscoreS;
    }
}

// ------------------------------------------------------------- launcher ----
extern "C" void kernel_launch(void* const* d_in, const int* in_sizes, int n_in,
                              void* d_out, int out_size, void* d_ws, size_t ws_size,
                              hipStream_t stream) {
    (void)in_sizes; (void)n_in; (void)out_size; (void)ws_size;
    const float* emb = (const float*)d_in[0];
    const float* cs  = (const float*)d_in[1];
    float* out = (float*)d_out;

    // workspace layout
    char* p = (char*)d_ws;
    float* cnorm  = (float*)p;  p += (size_t)N_CS * 4;                     // 64 KB
    float* pvals  = (float*)p;  p += (size_t)M_TOTAL * NTILES2 * 4;        // 1.6 MB
    int*   pidx   = (int*)p;    p += (size_t)M_TOTAL * NTILES2 * 4;        // 1.6 MB
    int*   loc    = (int*)p;    p += (size_t)M_TOTAL * 4;
    p = (char*)(((size_t)p + 7) & ~(size_t)7);
    unsigned long long* partial = (unsigned long long*)p; p += NBLK * 8;   // 12.5 KB
    float* kv     = (float*)p;  p += BATCH * KSL * KNN * 4;                // 4.6 KB
    int*   ki     = (int*)p;    p += BATCH * KSL * KNN * 4;                // 4.6 KB
    p = (char*)(((size_t)p + 15) & ~(size_t)15);
    _Float16* embh = (_Float16*)p; p += (size_t)M_TOTAL * D_DIM * 2;       // 4.8 MB
    _Float16* csh  = (_Float16*)p; p += (size_t)N_CS * D_DIM * 2;          // 12.6 MB

    {
        int rows = N_CS + M_TOTAL;
        convert_all_kernel<<<(rows + 3) / 4, 256, 0, stream>>>(emb, cs, embh, csh, cnorm);
    }
    mindist_mfma_kernel<<<MTILES * NTILES2, 256, 0, stream>>>(embh, csh, cnorm,
                                                              pvals, pidx);
    reduce_rescore_kernel<<<NBLK, 256, 0, stream>>>(pvals, pidx, emb, cs, loc, partial);
    knn_partial_kernel<<<BATCH * KSL, 256, 0, stream>>>(cs, cnorm, partial, loc, kv, ki);
    knn_final_kernel<<<BATCH, 512, 0, stream>>>(kv, ki, emb, cs, partial, out);
}

// Round 13
// 356.896 us; speedup vs baseline: 2.8098x; 1.2580x over previous
//
#include <hip/hip_runtime.h>
#include <hip/hip_bf16.h>
#include <math.h>

// Problem constants (fixed by setup_inputs)
#define M_TOTAL 6272   // B*P
#define N_CS    16384  // coreset rows
#define D_DIM   384
#define BATCH   8
#define P_PATCH 784
#define KNN     9

// MFMA GEMM tiling: 128x256 tile, 4 waves (2x2 of 64x128), BK=32, dbuf (R9)
#define MTILES  (M_TOTAL / 128)  // 49
#define NTILES2 (N_CS / 256)     // 64 -> pvals[m][64]
#define NBLK    (M_TOTAL / 4)    // 1568 reduce blocks; 784=4*196 -> one batch/block
#define PBB     196              // partial entries per batch
#define KSL     16               // top9 slices per batch (1024 cols each)

typedef _Float16 half8 __attribute__((ext_vector_type(8)));
typedef float    floatx4 __attribute__((ext_vector_type(4)));

// async global->LDS, 16B per lane; LDS dest must be uniform-base + lane*16
__device__ __forceinline__ void async_copy16(const void* g, void* l) {
    __builtin_amdgcn_global_load_lds(
        (const __attribute__((address_space(1))) void*)g,
        (__attribute__((address_space(3))) void*)l, 16, 0, 0);
}

__device__ __forceinline__ unsigned long long shfl_xor_u64(unsigned long long v, int mk) {
    int lo = __shfl_xor((int)(unsigned)v, mk, 64);
    int hi = __shfl_xor((int)(unsigned)(v >> 32), mk, 64);
    return ((unsigned long long)(unsigned)hi << 32) | (unsigned)lo;
}

// ---------------- convert fp32->f16, fused cs+emb (wave per row) ----------
__global__ void convert_all_kernel(const float* __restrict__ emb,
                                   const float* __restrict__ cs,
                                   _Float16* __restrict__ embh,
                                   _Float16* __restrict__ csh,
                                   float* __restrict__ cnorm) {
    int w = threadIdx.x >> 6, lane = threadIdx.x & 63;
    int row = blockIdx.x * 4 + w;
    if (row >= N_CS + M_TOTAL) return;
    bool is_cs = row < N_CS;
    const float* r = (is_cs ? cs + (size_t)row * D_DIM
                            : emb + (size_t)(row - N_CS) * D_DIM) + lane * 6;
    float2 a = *(const float2*)r;
    float2 b = *(const float2*)(r + 2);
    float2 c = *(const float2*)(r + 4);
    union { _Float16 h[2]; unsigned u; } p0, p1, p2;
    p0.h[0] = (_Float16)a.x; p0.h[1] = (_Float16)a.y;
    p1.h[0] = (_Float16)b.x; p1.h[1] = (_Float16)b.y;
    p2.h[0] = (_Float16)c.x; p2.h[1] = (_Float16)c.y;
    unsigned* dst = (unsigned*)(is_cs ? csh + (size_t)row * D_DIM
                                      : embh + (size_t)(row - N_CS) * D_DIM) + lane * 3;
    dst[0] = p0.u; dst[1] = p1.u; dst[2] = p2.u;
    if (is_cs) {
        float s = a.x * a.x + a.y * a.y + b.x * b.x + b.y * b.y + c.x * c.x + c.y * c.y;
#pragma unroll
        for (int mk = 1; mk <= 32; mk <<= 1) s += __shfl_xor(s, mk, 64);
        if (lane == 0) cnorm[row] = s;
    }
}

// --------------------------------------------- MFMA GEMM + min/argmin ----
// R9 config verbatim (best measured: 137 us). 128x256 tile, BK=32, dbuf
// with loads issued AFTER the drain barrier; XCD remap; XOR swizzle.
// R6: never raise launch_bounds (VGPR squeeze -> acc spill).
// R10: no direct global->VGPR fragments (16-line gathers, 245 us).
// R11: acc must stay <=128 VGPR/wave at 2 waves/SIMD.
// R12: never shuffle-reduce one dot per wave (knn_partial, 149 us).
__global__ __launch_bounds__(256, 2) void mindist_mfma_kernel(
    const _Float16* __restrict__ embh, const _Float16* __restrict__ csh,
    const float* __restrict__ cnorm,
    float* __restrict__ pvals, int* __restrict__ pidx) {
    __shared__ _Float16 As0[128 * 32];   // 8 KB
    __shared__ _Float16 As1[128 * 32];   // 8 KB
    __shared__ _Float16 Bs0[256 * 32];   // 16 KB
    __shared__ _Float16 Bs1[256 * 32];   // 16 KB

    const int b    = blockIdx.x;
    const int bx   = b >> 6;                               // 0..48
    const int by   = ((b & 7) << 3) | ((b >> 3) & 7);      // 0..63 (XCD-major)
    const int tid  = threadIdx.x;
    const int lane = tid & 63;
    const int w    = tid >> 6;
    const int wr   = w >> 1, wc = w & 1;
    const int row0  = bx * 128;
    const int cbase = by * 256;
    const int q   = lane >> 4;
    const int cl  = lane & 15;

    floatx4 acc[4][8];
#pragma unroll
    for (int mi = 0; mi < 4; ++mi)
#pragma unroll
        for (int nj = 0; nj < 8; ++nj) acc[mi][nj] = (floatx4){0.f, 0.f, 0.f, 0.f};

    float cn_l[8];
#pragma unroll
    for (int nj = 0; nj < 8; ++nj)
        cn_l[nj] = cnorm[cbase + wc * 128 + nj * 16 + cl];

    const int sub4 = lane >> 2;         // row within 16-row staging block
    const int ch   = lane & 3;          // dest 16B chunk

#define STAGE(AS, BS, KK)                                                     \
    {                                                                         \
        _Pragma("unroll")                                                     \
        for (int i = 0; i < 6; ++i) {                                         \
            int inst = w * 6 + i;                                             \
            if (inst < 8) {                                                   \
                int r  = inst * 16 + sub4;                                    \
                int sc = (ch ^ ((r >> 1) & 3)) * 8;                           \
                async_copy16(embh + (size_t)(row0 + r) * D_DIM + (KK) + sc,   \
                             &AS[inst * 512 + lane * 8]);                     \
            } else {                                                          \
                int blk = inst - 8;                                           \
                int r   = blk * 16 + sub4;                                    \
                int sc  = (ch ^ ((r >> 1) & 3)) * 8;                          \
                async_copy16(csh + (size_t)(cbase + r) * D_DIM + (KK) + sc,   \
                             &BS[blk * 512 + lane * 8]);                      \
            }                                                                 \
        }                                                                     \
    }

#define COMPUTE(AS, BS)                                                       \
    {                                                                         \
        half8 af[4], bf[8];                                                   \
        _Pragma("unroll")                                                     \
        for (int mi = 0; mi < 4; ++mi) {                                      \
            int R = wr * 64 + mi * 16 + cl;                                   \
            af[mi] = *(const half8*)&AS[R * 32 + ((q ^ ((R >> 1) & 3)) * 8)]; \
        }                                                                     \
        _Pragma("unroll")                                                     \
        for (int nj = 0; nj < 8; ++nj) {                                      \
            int R = wc * 128 + nj * 16 + cl;                                  \
            bf[nj] = *(const half8*)&BS[R * 32 + ((q ^ ((R >> 1) & 3)) * 8)]; \
        }                                                                     \
        _Pragma("unroll")                                                     \
        for (int mi = 0; mi < 4; ++mi)                                        \
            _Pragma("unroll")                                                 \
            for (int nj = 0; nj < 8; ++nj)                                    \
                acc[mi][nj] = __builtin_amdgcn_mfma_f32_16x16x32_f16(         \
                    af[mi], bf[nj], acc[mi][nj], 0, 0, 0);                    \
    }

    STAGE(As0, Bs0, 0);
    int kk = 0;
#pragma unroll 1
    for (int jj = 0; jj < 5; ++jj) {
        __syncthreads();                 // drain chunk kk (buf0)
        STAGE(As1, Bs1, kk + 32);        // prefetch: flies during compute
        COMPUTE(As0, Bs0);
        __syncthreads();                 // drain chunk kk+32 (buf1)
        STAGE(As0, Bs0, kk + 64);
        COMPUTE(As1, Bs1);
        kk += 64;
    }
    __syncthreads();
    STAGE(As1, Bs1, kk + 32);
    COMPUTE(As0, Bs0);
    __syncthreads();
    COMPUTE(As1, Bs1);
#undef STAGE
#undef COMPUTE

    __syncthreads();
    float* smv = (float*)As0;           // [128][2] (1 KB)
    int*   smi = (int*)(As0 + 512);     // 1 KB past smv

#pragma unroll
    for (int mi = 0; mi < 4; ++mi) {
#pragma unroll
        for (int r = 0; r < 4; ++r) {
            float v = 3.4e38f; int idx = 0x7fffffff;
#pragma unroll
            for (int nj = 0; nj < 8; ++nj) {   // ascending col per lane, strict <
                float d = cn_l[nj] - 2.f * acc[mi][nj][r];
                int   c = cbase + wc * 128 + nj * 16 + cl;
                if (d < v) { v = d; idx = c; }
            }
#pragma unroll
            for (int mk = 1; mk <= 8; mk <<= 1) {
                float v2 = __shfl_xor(v, mk, 64);
                int   i2 = __shfl_xor(idx, mk, 64);
                if (v2 < v || (v2 == v && i2 < idx)) { v = v2; idx = i2; }
            }
            if (cl == 0) {
                int rl = wr * 64 + mi * 16 + q * 4 + r;
                smv[rl * 2 + wc] = v;
                smi[rl * 2 + wc] = idx;
            }
        }
    }
    __syncthreads();
    if (tid < 128) {
        float v = smv[tid * 2];      int i = smi[tid * 2];
        float v1 = smv[tid * 2 + 1]; int i1 = smi[tid * 2 + 1];
        if (v1 < v) { v = v1; i = i1; }   // wc0 indices always < wc1 indices
        pvals[(size_t)(row0 + tid) * NTILES2 + by] = v;
        pidx[(size_t)(row0 + tid) * NTILES2 + by]  = i;
    }
}

// ---- partial-min reduce + EXACT fp32 rescore + block-level argmax -------
// NO atomics (R7: device atomicMax on one line bounced across XCDs, ~65 us).
__global__ void reduce_rescore_kernel(const float* __restrict__ pvals,
                                      const int* __restrict__ pidx,
                                      const float* __restrict__ emb,
                                      const float* __restrict__ cs,
                                      int* __restrict__ loc,
                                      unsigned long long* __restrict__ partial) {
    __shared__ unsigned long long keys[4];
    int w = threadIdx.x >> 6, lane = threadIdx.x & 63;
    int m = blockIdx.x * 4 + w;
    float v = pvals[(size_t)m * NTILES2 + lane];
    int   i = pidx[(size_t)m * NTILES2 + lane];
#pragma unroll
    for (int mk = 1; mk <= 32; mk <<= 1) {
        float v2 = __shfl_xor(v, mk, 64);
        int   i2 = __shfl_xor(i, mk, 64);
        if (v2 < v || (v2 == v && i2 < i)) { v = v2; i = i2; }
    }
    const float* a = emb + (size_t)m * D_DIM;
    const float* bp = cs + (size_t)i * D_DIM;
    float s = 0.f;
#pragma unroll
    for (int t = 0; t < D_DIM / 64; ++t) {
        float d = a[lane + t * 64] - bp[lane + t * 64];
        s += d * d;
    }
#pragma unroll
    for (int mk = 1; mk <= 32; mk <<= 1) s += __shfl_xor(s, mk, 64);
    if (lane == 0) {
        float sc = sqrtf(s);
        loc[m] = i;
        int p = m % P_PATCH;
        keys[w] = ((unsigned long long)__float_as_uint(sc) << 32) |
                  (unsigned)(0x7fffffff - p);
    }
    __syncthreads();
    if (threadIdx.x == 0) {
        unsigned long long k = keys[0];
        if (keys[1] > k) k = keys[1];
        if (keys[2] > k) k = keys[2];
        if (keys[3] > k) k = keys[3];
        partial[blockIdx.x] = k;
    }
}

// ----------- d_nn via MFMA: 8 queries (pad 16) x coreset, -> dmat --------
// R13: replaces shuffle-GEMV (R12: 149 us, 6-deep dependent shfl chain per
// row). A (queries) lives in registers for the whole kernel (12 chunk-
// frags, L2-hot, identical across blocks); only B staged per chunk. 64
// blocks x 4 waves; wave covers 64 cols as 4 16x16 tiles.
__global__ void dnn_mfma_kernel(const _Float16* __restrict__ csh,
                                const float* __restrict__ cnorm,
                                const unsigned long long* __restrict__ partial,
                                const int* __restrict__ loc,
                                float* __restrict__ dmat) {
    __shared__ _Float16 Bs[256 * 32];   // 16 KB
    __shared__ int bnnS[BATCH];

    const int tid  = threadIdx.x;
    const int lane = tid & 63;
    const int w    = tid >> 6;
    const int cbase = blockIdx.x * 256;
    const int q   = lane >> 4;
    const int cl  = lane & 15;

    {   // recompute per-batch argmax -> nn row index (32 lanes per batch)
        int bb = tid >> 5, l32 = tid & 31;
        unsigned long long best = 0ull;
        for (int j = l32; j < PBB; j += 32) {
            unsigned long long k = partial[bb * PBB + j];
            if (k > best) best = k;
        }
#pragma unroll
        for (int mk = 1; mk <= 16; mk <<= 1) {
            unsigned long long o = shfl_xor_u64(best, mk);
            if (o > best) best = o;
        }
        if (l32 == 0) {
            int p = 0x7fffffff - (unsigned)(best & 0xffffffffull);
            bnnS[bb] = loc[bb * P_PATCH + p];
        }
    }
    __syncthreads();

    // A fragments in registers: row = query (cl&7; rows 8..15 dup row 0-7)
    const _Float16* arow = csh + (size_t)bnnS[cl & 7] * D_DIM + q * 8;
    half8 af[12];
#pragma unroll
    for (int c = 0; c < 12; ++c) af[c] = *(const half8*)(arow + c * 32);

    floatx4 acc[4];
#pragma unroll
    for (int t = 0; t < 4; ++t) acc[t] = (floatx4){0.f, 0.f, 0.f, 0.f};

    const int sub4 = lane >> 2;
    const int ch   = lane & 3;

#pragma unroll 1
    for (int c = 0; c < 12; ++c) {
        __syncthreads();
#pragma unroll
        for (int i = 0; i < 8; ++i) {
            int blk = w * 8 + i;            // 0..31: 256 rows
            int r   = blk * 16 + sub4;
            int sc  = (ch ^ ((r >> 1) & 3)) * 8;
            async_copy16(csh + (size_t)(cbase + r) * D_DIM + c * 32 + sc,
                         &Bs[blk * 512 + lane * 8]);
        }
        __syncthreads();
#pragma unroll
        for (int t = 0; t < 4; ++t) {
            int R = w * 64 + t * 16 + cl;
            half8 bf = *(const half8*)&Bs[R * 32 + ((q ^ ((R >> 1) & 3)) * 8)];
            acc[t] = __builtin_amdgcn_mfma_f32_16x16x32_f16(af[c], bf, acc[t], 0, 0, 0);
        }
    }

    // epilogue: m = q*4 + r (batch, valid m<8); n = cbase + w*64 + t*16 + cl
#pragma unroll
    for (int t = 0; t < 4; ++t) {
#pragma unroll
        for (int r = 0; r < 4; ++r) {
            int m = q * 4 + r;
            if (m < BATCH) {
                int n = cbase + w * 64 + t * 16 + cl;
                dmat[(size_t)m * N_CS + n] = cnorm[n] - 2.f * acc[t][r];
            }
        }
    }
}

// ------------- top-9 partial over dmat slices (reads, no recompute) ------
__device__ inline void merge9(float* av, int* ai, const float* bv, const int* bi) {
    float mv[KNN]; int mi[KNN];
    int x = 0, y = 0;
#pragma unroll
    for (int k = 0; k < KNN; ++k) {
        bool ta = (av[x] < bv[y]) || (av[x] == bv[y] && ai[x] < bi[y]);
        if (ta) { mv[k] = av[x]; mi[k] = ai[x]; ++x; }
        else    { mv[k] = bv[y]; mi[k] = bi[y]; ++y; }
    }
#pragma unroll
    for (int k = 0; k < KNN; ++k) { av[k] = mv[k]; ai[k] = mi[k]; }
}

__global__ void top9_partial_kernel(const float* __restrict__ dmat,
                                    float* __restrict__ kv, int* __restrict__ ki) {
    const int blk = blockIdx.x;          // 0..127
    const int bb  = blk >> 4;            // batch
    const int sl  = blk & 15;            // slice of 1024 cols
    const int tid = threadIdx.x;         // 256
    __shared__ float lv[256][KNN];
    __shared__ int   li[256][KNN];

    float tv[KNN]; int ti[KNN];
#pragma unroll
    for (int k = 0; k < KNN; ++k) { tv[k] = 3.4e38f; ti[k] = 0x7fffffff; }
    const int base = sl * 1024 + tid * 4;
#pragma unroll
    for (int j = 0; j < 4; ++j) {        // contiguous, ascending n
        int n = base + j;
        float d = dmat[(size_t)bb * N_CS + n];
        if (d < tv[KNN - 1] || (d == tv[KNN - 1] && n < ti[KNN - 1])) {
            tv[KNN - 1] = d; ti[KNN - 1] = n;
#pragma unroll
            for (int k = KNN - 1; k > 0; --k) {
                if (tv[k] < tv[k - 1] || (tv[k] == tv[k - 1] && ti[k] < ti[k - 1])) {
                    float fv = tv[k]; tv[k] = tv[k - 1]; tv[k - 1] = fv;
                    int   iv = ti[k]; ti[k] = ti[k - 1]; ti[k - 1] = iv;
                }
            }
        }
    }
#pragma unroll
    for (int k = 0; k < KNN; ++k) { lv[tid][k] = tv[k]; li[tid][k] = ti[k]; }
    __syncthreads();
    for (int off = 128; off > 0; off >>= 1) {
        if (tid < off) {
            float av[KNN]; int ai[KNN]; float bv2[KNN]; int bi2[KNN];
#pragma unroll
            for (int k = 0; k < KNN; ++k) {
                av[k]  = lv[tid][k];        ai[k]  = li[tid][k];
                bv2[k] = lv[tid + off][k];  bi2[k] = li[tid + off][k];
            }
            merge9(av, ai, bv2, bi2);
#pragma unroll
            for (int k = 0; k < KNN; ++k) { lv[tid][k] = av[k]; li[tid][k] = ai[k]; }
        }
        __syncthreads();
    }
    if (tid < KNN) {
        kv[blk * KNN + tid] = lv[0][tid];
        ki[blk * KNN + tid] = li[0][tid];
    }
}

// ---------- knn final: merge 16x9 candidates + exact dsup + softmax ------
__global__ void knn_final_kernel(const float* __restrict__ kv,
                                 const int* __restrict__ ki,
                                 const float* __restrict__ emb,
                                 const float* __restrict__ cs,
                                 const unsigned long long* __restrict__ partial,
                                 float* __restrict__ out) {
    const int b = blockIdx.x;
    const int tid = threadIdx.x;   // 512
    const int NCAND = KSL * KNN;   // 144
    __shared__ float cv[NCAND];
    __shared__ int   ci[NCAND];
    __shared__ float mf[D_DIM];
    __shared__ int   sel[KNN];
    __shared__ float dsup[KNN];
    __shared__ float bscoreS;
    __shared__ int   bpatchS;

    if (tid < 64) {   // argmax recompute
        unsigned long long best = 0ull;
        for (int j = tid; j < PBB; j += 64) {
            unsigned long long k = partial[b * PBB + j];
            if (k > best) best = k;
        }
#pragma unroll
        for (int mk = 1; mk <= 32; mk <<= 1) {
            unsigned long long o = shfl_xor_u64(best, mk);
            if (o > best) best = o;
        }
        if (tid == 0) {
            bpatchS = 0x7fffffff - (unsigned)(best & 0xffffffffull);
            bscoreS = __uint_as_float((unsigned)(best >> 32));
        }
    }
    if (tid < NCAND) {
        cv[tid] = kv[b * NCAND + tid];
        ci[tid] = ki[b * NCAND + tid];
    }
    __syncthreads();
    const float* frow = emb + (size_t)(b * P_PATCH + bpatchS) * D_DIM;
    for (int i = tid; i < D_DIM; i += 512) mf[i] = frow[i];

    if (tid == 0) {   // serial select-9 from 144 (disjoint candidate sets)
        for (int k = 0; k < KNN; ++k) {
            float bv = 3.4e38f; int bi = 0x7fffffff; int bj = -1;
            for (int j = 0; j < NCAND; ++j) {
                if (cv[j] < bv || (cv[j] == bv && ci[j] < bi)) {
                    bv = cv[j]; bi = ci[j]; bj = j;
                }
            }
            sel[k] = bi;
            cv[bj] = 3.4e38f; ci[bj] = 0x7fffffff;
        }
    }
    __syncthreads();
    {
        int k = tid >> 5, lane32 = tid & 31;
        if (k < KNN) {
            const float* r = cs + (size_t)sel[k] * D_DIM;
            float s = 0.f;
            for (int i = lane32; i < D_DIM; i += 32) {
                float df = mf[i] - r[i];
                s += df * df;
            }
#pragma unroll
            for (int mk = 1; mk <= 16; mk <<= 1) s += __shfl_xor(s, mk, 64);
            if (lane32 == 0) dsup[k] = sqrtf(fmaxf(s, 0.f));
        }
    }
    __syncthreads();
    if (tid == 0) {
        float mx = dsup[0];
        for (int k = 1; k < KNN; ++k) mx = fmaxf(mx, dsup[k]);
        float sum = 0.f, e0 = 0.f;
        for (int k = 0; k < KNN; ++k) {
            float e = expf(dsup[k] - mx);
            sum += e;
            if (k == 0) e0 = e;
        }
        out[b] = (1.f - e0 / sum) * bscoreS;
    }
}

// ------------------------------------------------------------- launcher ----
extern "C" void kernel_launch(void* const* d_in, const int* in_sizes, int n_in,
                              void* d_out, int out_size, void* d_ws, size_t ws_size,
                              hipStream_t stream) {
    (void)in_sizes; (void)n_in; (void)out_size; (void)ws_size;
    const float* emb = (const float*)d_in[0];
    const float* cs  = (const float*)d_in[1];
    float* out = (float*)d_out;

    // workspace layout
    char* p = (char*)d_ws;
    float* cnorm  = (float*)p;  p += (size_t)N_CS * 4;                     // 64 KB
    float* pvals  = (float*)p;  p += (size_t)M_TOTAL * NTILES2 * 4;        // 1.6 MB
    int*   pidx   = (int*)p;    p += (size_t)M_TOTAL * NTILES2 * 4;        // 1.6 MB
    int*   loc    = (int*)p;    p += (size_t)M_TOTAL * 4;
    p = (char*)(((size_t)p + 7) & ~(size_t)7);
    unsigned long long* partial = (unsigned long long*)p; p += NBLK * 8;   // 12.5 KB
    float* dmat   = (float*)p;  p += (size_t)BATCH * N_CS * 4;             // 512 KB
    float* kv     = (float*)p;  p += BATCH * KSL * KNN * 4;                // 4.6 KB
    int*   ki     = (int*)p;    p += BATCH * KSL * KNN * 4;                // 4.6 KB
    p = (char*)(((size_t)p + 15) & ~(size_t)15);
    _Float16* embh = (_Float16*)p; p += (size_t)M_TOTAL * D_DIM * 2;       // 4.8 MB
    _Float16* csh  = (_Float16*)p; p += (size_t)N_CS * D_DIM * 2;          // 12.6 MB

    {
        int rows = N_CS + M_TOTAL;
        convert_all_kernel<<<(rows + 3) / 4, 256, 0, stream>>>(emb, cs, embh, csh, cnorm);
    }
    mindist_mfma_kernel<<<MTILES * NTILES2, 256, 0, stream>>>(embh, csh, cnorm,
                                                              pvals, pidx);
    reduce_rescore_kernel<<<NBLK, 256, 0, stream>>>(pvals, pidx, emb, cs, loc, partial);
    dnn_mfma_kernel<<<N_CS / 256, 256, 0, stream>>>(csh, cnorm, partial, loc, dmat);
    top9_partial_kernel<<<BATCH * KSL, 256, 0, stream>>>(dmat, kv, ki);
    knn_final_kernel<<<BATCH, 512, 0, stream>>>(kv, ki, emb, cs, partial, out);
}